// Round 8
// baseline (560.562 us; speedup 1.0000x reference)
//
#include <hip/hip_runtime.h>

typedef short short8 __attribute__((ext_vector_type(8)));
typedef float f32x4 __attribute__((ext_vector_type(4)));
typedef unsigned short us4 __attribute__((ext_vector_type(4)));
typedef unsigned short u16;

#define MFMA(a,b,c) __builtin_amdgcn_mfma_f32_16x16x32_bf16((a),(b),(c),0,0,0)

__device__ __forceinline__ u16 f2b(float f) {
    union { float f; unsigned int i; } v; v.f = f;
    unsigned int x = v.i;
    return (u16)((x + 0x7fffu + ((x >> 16) & 1u)) >> 16);
}

// pack two f32 -> one dword of 2 bf16 using the same RNE rounding as f2b
__device__ __forceinline__ unsigned int pk2(float lo, float hi) {
    return (unsigned int)f2b(lo) | ((unsigned int)f2b(hi) << 16);
}

// ---- all weights -> bf16, k-chunked layout [k>>5][256 n][32 k] (16 KB contiguous chunks);
// W1/W2 additionally permuted to channel-planar k' ----
__global__ __launch_bounds__(256) void k_wtrans(const float* __restrict__ W1,
        const float* __restrict__ W2, const float* __restrict__ Wq, const float* __restrict__ Wk,
        const float* __restrict__ Wv, const float* __restrict__ Wp,
        u16* __restrict__ w1t, u16* __restrict__ w2t, u16* __restrict__ wqt,
        u16* __restrict__ wkt, u16* __restrict__ wvt, u16* __restrict__ wpt) {
    int bx = blockIdx.x, n = threadIdx.x;
    if (bx < 768) {
        int k = bx, c = k % 3, t = k / 3, pj = t & 15, pi = t >> 4;
        int kp2 = c*256 + pi*16 + pj;
        w1t[(size_t)(kp2 >> 5)*8192 + n*32 + (kp2 & 31)] = f2b(W1[(size_t)k*256 + n]);
    } else if (bx < 960) {
        int k = bx - 768, c = k % 3, t = k / 3, pj = t & 7, pi = t >> 3;
        int kp2 = c*64 + pi*8 + pj;
        w2t[(size_t)(kp2 >> 5)*8192 + n*32 + (kp2 & 31)] = f2b(W2[(size_t)k*256 + n]);
    } else if (bx < 1216) { int k = bx - 960;  wqt[(size_t)(k>>5)*8192 + n*32 + (k&31)] = f2b(Wq[(size_t)k*256 + n]); }
    else if (bx < 1472)   { int k = bx - 1216; wkt[(size_t)(k>>5)*8192 + n*32 + (k&31)] = f2b(Wk[(size_t)k*256 + n]); }
    else if (bx < 1728)   { int k = bx - 1472; wvt[(size_t)(k>>5)*8192 + n*32 + (k&31)] = f2b(Wv[(size_t)k*256 + n]); }
    else                  { int k = bx - 1728; wpt[(size_t)(k>>5)*8192 + n*32 + (k&31)] = f2b(Wp[(size_t)k*256 + n]); }
}

// ---- cls tokens (0 = cls2, 197 = cls1) into z, fused LN1 -> h ----
__global__ __launch_bounds__(256) void k_cls(const float* __restrict__ cls1,
        const float* __restrict__ cls2, const float* __restrict__ g1, const float* __restrict__ be1,
        float* __restrict__ z, u16* __restrict__ h) {
    __shared__ float red[16];
    int b = blockIdx.x, e = threadIdx.x, lane = e & 63, w = e >> 6;
    float v0 = cls2[e], v1 = cls1[e];
    z[((size_t)b*394 + 0)*256 + e]   = v0;
    z[((size_t)b*394 + 197)*256 + e] = v1;
    float s0 = v0, q0 = v0*v0, s1 = v1, q1 = v1*v1;
    #pragma unroll
    for (int m = 1; m < 64; m <<= 1) {
        s0 += __shfl_xor(s0, m); q0 += __shfl_xor(q0, m);
        s1 += __shfl_xor(s1, m); q1 += __shfl_xor(q1, m);
    }
    if (lane == 0) { red[w] = s0; red[4+w] = q0; red[8+w] = s1; red[12+w] = q1; }
    __syncthreads();
    float S0 = red[0]+red[1]+red[2]+red[3],   Q0 = red[4]+red[5]+red[6]+red[7];
    float S1 = red[8]+red[9]+red[10]+red[11], Q1 = red[12]+red[13]+red[14]+red[15];
    float m0 = S0*(1.f/256.f), r0 = rsqrtf(Q0*(1.f/256.f) - m0*m0 + 1e-5f);
    float m1 = S1*(1.f/256.f), r1 = rsqrtf(Q1*(1.f/256.f) - m1*m1 + 1e-5f);
    h[((size_t)b*394 + 0)*256 + e]   = f2b((v0-m0)*r0*g1[e] + be1[e]);
    h[((size_t)b*394 + 197)*256 + e] = f2b((v1-m1)*r1*g1[e] + be1[e]);
}

// ---- im2col for P=16 patches: x -> A1 [bc*208][768] bf16 (k' = c*256+pi*16+pj),
// pad rows (j>=196) zeroed. Fully packed 16B stores. ----
__global__ __launch_bounds__(256) void k_im2col1(const float* __restrict__ x,
        u16* __restrict__ A1) {
    int b = blockIdx.y, g = blockIdx.x, tid = threadIdx.x;
    int p = tid >> 4, pi = tid & 15;
    int j = g*16 + p;
    u16* dst = A1 + ((size_t)b*208 + j)*768;
    if (j < 196) {
        int hi = j / 14, wi = j - hi*14;
        #pragma unroll
        for (int c = 0; c < 3; ++c) {
            const float* src = x + (((size_t)b*3 + c)*224 + hi*16 + pi)*224 + wi*16;
            f32x4 r0 = *(const f32x4*)(src);
            f32x4 r1 = *(const f32x4*)(src + 4);
            f32x4 r2 = *(const f32x4*)(src + 8);
            f32x4 r3 = *(const f32x4*)(src + 12);
            union { u16 u[16]; uint4 q[2]; } t;
            #pragma unroll
            for (int s = 0; s < 4; ++s) {
                t.u[s] = f2b(r0[s]); t.u[4+s] = f2b(r1[s]);
                t.u[8+s] = f2b(r2[s]); t.u[12+s] = f2b(r3[s]);
            }
            *(uint4*)&dst[c*256 + pi*16] = t.q[0];
            *(uint4*)&dst[c*256 + pi*16 + 8] = t.q[1];
        }
    } else {
        uint4 zer = {0,0,0,0};
        #pragma unroll
        for (int c = 0; c < 3; ++c) {
            *(uint4*)&dst[c*256 + pi*16] = zer;
            *(uint4*)&dst[c*256 + pi*16 + 8] = zer;
        }
    }
}

// ---- embed1 GEMM: [nrows x 768] x [768 x 256], M-tile 64, A/B LDS double-buffered,
// register prefetch 2 chunks deep, fused LN1 -> z, h ----
__global__ __launch_bounds__(256) void k_embed1(const u16* __restrict__ A1,
        const u16* __restrict__ w1t, const float* __restrict__ b1,
        const float* __restrict__ g1, const float* __restrict__ be1,
        float* __restrict__ z, u16* __restrict__ h, int nrows) {
    __shared__ __align__(16) u16 Ab[2][64*40];     // 10,240 B
    __shared__ __align__(16) u16 Bb[2][256*40];    // 40,960 B
    __shared__ float red[64][8];                   //  2,048 B
    int tid = threadIdx.x;
    int r0 = blockIdx.x * 64;
    int w = tid >> 6, lane = tid & 63, quad = lane >> 4, tf = lane & 15;
    int arow = tid >> 2, aoff = (tid & 3) * 8;
    const u16* ap = A1 + (size_t)(r0 + arow)*768 + aoff;
    uint4 ra[2];
    uint4 rb[2][4];
    auto pload = [&](int set, int c) {
        ra[set] = *(const uint4*)(ap + c*32);
        const u16* src = w1t + (size_t)c*8192;
        rb[set][0] = *(const uint4*)&src[tid*8];
        rb[set][1] = *(const uint4*)&src[2048 + tid*8];
        rb[set][2] = *(const uint4*)&src[4096 + tid*8];
        rb[set][3] = *(const uint4*)&src[6144 + tid*8];
    };
    pload(0, 0);
    pload(1, 1);
    f32x4 zero = {0.f,0.f,0.f,0.f};
    f32x4 acc[4][4];
    #pragma unroll
    for (int m = 0; m < 4; ++m)
        #pragma unroll
        for (int nf = 0; nf < 4; ++nf) acc[m][nf] = zero;
    #pragma unroll
    for (int kc = 0; kc < 24; ++kc) {
        int buf = kc & 1;
        *(uint4*)&Ab[buf][arow*40 + aoff] = ra[buf];
        *(uint4*)&Bb[buf][(arow      )*40 + aoff] = rb[buf][0];
        *(uint4*)&Bb[buf][(arow +  64)*40 + aoff] = rb[buf][1];
        *(uint4*)&Bb[buf][(arow + 128)*40 + aoff] = rb[buf][2];
        *(uint4*)&Bb[buf][(arow + 192)*40 + aoff] = rb[buf][3];
        if (kc + 2 < 24) pload(buf, kc + 2);
        __syncthreads();
        short8 a0 = *(const short8*)&Ab[buf][(     tf)*40 + quad*8];
        short8 a1 = *(const short8*)&Ab[buf][(16 + tf)*40 + quad*8];
        short8 a2 = *(const short8*)&Ab[buf][(32 + tf)*40 + quad*8];
        short8 a3 = *(const short8*)&Ab[buf][(48 + tf)*40 + quad*8];
        #pragma unroll
        for (int nf = 0; nf < 4; ++nf) {
            short8 bb = *(const short8*)&Bb[buf][(w*64 + nf*16 + tf)*40 + quad*8];
            acc[0][nf] = MFMA(a0, bb, acc[0][nf]);
            acc[1][nf] = MFMA(a1, bb, acc[1][nf]);
            acc[2][nf] = MFMA(a2, bb, acc[2][nf]);
            acc[3][nf] = MFMA(a3, bb, acc[3][nf]);
        }
    }
    // epilogue: bias, per-row LN via tf-shuffle partials + cross-wave LDS
    float bias[4], gv[4], bev[4];
    #pragma unroll
    for (int nf = 0; nf < 4; ++nf) {
        int n = w*64 + nf*16 + tf;
        bias[nf] = b1[n]; gv[nf] = g1[n]; bev[nf] = be1[n];
    }
    #pragma unroll
    for (int m = 0; m < 4; ++m)
        #pragma unroll
        for (int nf = 0; nf < 4; ++nf)
            #pragma unroll
            for (int i = 0; i < 4; ++i) acc[m][nf][i] += bias[nf];
    #pragma unroll
    for (int m = 0; m < 4; ++m)
        #pragma unroll
        for (int i = 0; i < 4; ++i) {
            float s = acc[m][0][i] + acc[m][1][i] + acc[m][2][i] + acc[m][3][i];
            float qv = acc[m][0][i]*acc[m][0][i] + acc[m][1][i]*acc[m][1][i]
                     + acc[m][2][i]*acc[m][2][i] + acc[m][3][i]*acc[m][3][i];
            #pragma unroll
            for (int d = 1; d < 16; d <<= 1) { s += __shfl_xor(s, d); qv += __shfl_xor(qv, d); }
            if (tf == 0) {
                red[m*16 + quad*4 + i][w] = s;
                red[m*16 + quad*4 + i][4 + w] = qv;
            }
        }
    __syncthreads();
    #pragma unroll
    for (int m = 0; m < 4; ++m)
        #pragma unroll
        for (int i = 0; i < 4; ++i) {
            int rl = m*16 + quad*4 + i;
            float S = red[rl][0]+red[rl][1]+red[rl][2]+red[rl][3];
            float Q = red[rl][4]+red[rl][5]+red[rl][6]+red[rl][7];
            float mean = S*(1.f/256.f);
            float rs = rsqrtf(Q*(1.f/256.f) - mean*mean + 1e-5f);
            int row = r0 + rl;
            if (row < nrows) {
                int img = row / 208;
                int j = row - img*208;
                if (j < 196) {
                    size_t base = ((size_t)img*394 + 198 + j)*256;
                    #pragma unroll
                    for (int nf = 0; nf < 4; ++nf) {
                        int n = w*64 + nf*16 + tf;
                        float v = acc[m][nf][i];
                        z[base + n] = v;
                        h[base + n] = f2b((v - mean)*rs*gv[nf] + bev[nf]);
                    }
                }
            }
        }
}

// ---- patch embed P=8 sampled (tokens 1..196, patch=4*it-1) + fused LN1 ----
__global__ __launch_bounds__(256) void k_embed2(const float* __restrict__ x,
        const u16* __restrict__ w2t, const float* __restrict__ b2,
        const float* __restrict__ g1, const float* __restrict__ be1,
        float* __restrict__ z, u16* __restrict__ h) {
    __shared__ __align__(16) u16 A[16*200];
    __shared__ __align__(16) u16 Wst[8192];
    __shared__ __align__(16) float S[16*260];
    int b = blockIdx.y, g = blockIdx.x, tid = threadIdx.x;
    int p = tid >> 4, s16 = tid & 15;
    int pi = s16 >> 1, ph = s16 & 1;
    int it = g*16 + p + 1;
    uint4 wr0 = *(const uint4*)&w2t[tid*8];
    uint4 wr1 = *(const uint4*)&w2t[2048 + tid*8];
    uint4 wr2 = *(const uint4*)&w2t[4096 + tid*8];
    uint4 wr3 = *(const uint4*)&w2t[6144 + tid*8];
    auto stage = [&](const u16* base, int chunk) {
        __syncthreads();
        *(uint4*)&Wst[tid*8] = wr0;
        *(uint4*)&Wst[2048 + tid*8] = wr1;
        *(uint4*)&Wst[4096 + tid*8] = wr2;
        *(uint4*)&Wst[6144 + tid*8] = wr3;
        __syncthreads();
        if (base) {
            const u16* src = base + (size_t)chunk*8192;
            wr0 = *(const uint4*)&src[tid*8];
            wr1 = *(const uint4*)&src[2048 + tid*8];
            wr2 = *(const uint4*)&src[4096 + tid*8];
            wr3 = *(const uint4*)&src[6144 + tid*8];
        }
    };
    if (it <= 196) {
        int patch = 4*it - 1;
        int hi = patch / 28, wi = patch - hi*28;
        #pragma unroll
        for (int c = 0; c < 3; ++c) {
            const float* src = x + (((size_t)b*3 + c)*224 + hi*8 + pi)*224 + wi*8 + ph*4;
            f32x4 r = *(const f32x4*)src;
            us4 o; o[0] = f2b(r[0]); o[1] = f2b(r[1]); o[2] = f2b(r[2]); o[3] = f2b(r[3]);
            *(us4*)&A[p*200 + c*64 + pi*8 + ph*4] = o;
        }
    } else {
        us4 zer = {0,0,0,0};
        #pragma unroll
        for (int c = 0; c < 3; ++c)
            *(us4*)&A[p*200 + c*64 + pi*8 + ph*4] = zer;
    }
    int w = tid >> 6, lane = tid & 63, quad = lane >> 4, tf = lane & 15;
    f32x4 zero = {0.f,0.f,0.f,0.f};
    f32x4 acc[4] = {zero,zero,zero,zero};
    #pragma unroll
    for (int ks = 0; ks < 6; ++ks) {
        stage(ks < 5 ? w2t : nullptr, ks + 1);
        short8 a = *(const short8*)&A[tf*200 + ks*32 + quad*8];
        #pragma unroll
        for (int nf = 0; nf < 4; ++nf) {
            short8 bb = *(const short8*)&Wst[(w*64 + nf*16 + tf)*32 + quad*8];
            acc[nf] = MFMA(a, bb, acc[nf]);
        }
    }
    #pragma unroll
    for (int nf = 0; nf < 4; ++nf) {
        int n = w*64 + nf*16 + tf;
        float bias = b2[n];
        #pragma unroll
        for (int i = 0; i < 4; ++i)
            S[(quad*4 + i)*260 + n] = acc[nf][i] + bias;
    }
    __syncthreads();
    #pragma unroll
    for (int rr = 0; rr < 4; ++rr) {
        int row = w*4 + rr;
        int it2 = g*16 + row + 1;
        f32x4 v = *(const f32x4*)&S[row*260 + lane*4];
        float s = v[0]+v[1]+v[2]+v[3];
        float sq = v[0]*v[0]+v[1]*v[1]+v[2]*v[2]+v[3]*v[3];
        #pragma unroll
        for (int m = 1; m < 64; m <<= 1) { s += __shfl_xor(s, m); sq += __shfl_xor(sq, m); }
        float mean = s*(1.f/256.f);
        float rs = rsqrtf(sq*(1.f/256.f) - mean*mean + 1e-5f);
        if (it2 <= 196) {
            size_t base = ((size_t)b*394 + it2)*256 + lane*4;
            *(f32x4*)&z[base] = v;
            us4 ho;
            #pragma unroll
            for (int c = 0; c < 4; ++c) {
                int e = lane*4 + c;
                ho[c] = f2b((v[c]-mean)*rs*g1[e] + be1[e]);
            }
            *(us4*)&h[base] = ho;
        }
    }
}

// ---- coalesced epilogues: stage MFMA fragments through LDS, write full lines ----
__device__ __forceinline__ void store_qk(f32x4 acc[4][4], const float* __restrict__ bs,
        u16* __restrict__ dst, u16* Sst, int b, int mt, int w, int quad, int tf, int tid) {
    #pragma unroll
    for (int m = 0; m < 4; ++m) {
        __syncthreads();
        #pragma unroll
        for (int nf = 0; nf < 4; ++nf) {
            int e = w*64 + nf*16 + tf;
            float bias = bs[e];
            #pragma unroll
            for (int i = 0; i < 4; ++i) {
                int n = mt*64 + m*16 + quad*4 + i;
                Sst[(quad*4 + i)*264 + e] = (n < 394) ? f2b(acc[m][nf][i] + bias) : (u16)0;
            }
        }
        __syncthreads();
        int row = tid >> 4, c16 = tid & 15;
        int n = mt*64 + m*16 + row;
        if (n < 416) {
            int e0 = c16*16, hh = e0 >> 7, d0 = e0 & 127;
            uint4 v0 = *(const uint4*)&Sst[row*264 + e0];
            uint4 v1 = *(const uint4*)&Sst[row*264 + e0 + 8];
            u16* p = dst + ((size_t)(b*2 + hh)*416 + n)*128 + d0;
            *(uint4*)p = v0;
            *(uint4*)(p + 8) = v1;
        }
    }
}

__device__ __forceinline__ void store_v(f32x4 acc[4][4], const float* __restrict__ bs,
        u16* __restrict__ vt, u16* Sst, int b, int mt, int w, int quad, int tf, int tid) {
    #pragma unroll
    for (int nf = 0; nf < 4; ++nf) {
        __syncthreads();
        #pragma unroll
        for (int i = 0; i < 4; ++i) {
            int e = w*64 + nf*16 + quad*4 + i;
            float bias = bs[e];
            #pragma unroll
            for (int m = 0; m < 4; ++m) {
                int n = mt*64 + m*16 + tf;
                Sst[(w*16 + quad*4 + i)*72 + m*16 + tf] = (n < 394) ? f2b(acc[m][nf][i] + bias) : (u16)0;
            }
        }
        __syncthreads();
        #pragma unroll
        for (int k = 0; k < 2; ++k) {
            int ch = tid + k*256;
            int row = ch >> 3, c8 = ch & 7;
            int n0 = mt*64 + c8*8;
            if (n0 < 416) {
                int e = (row >> 4)*64 + nf*16 + (row & 15);
                int d = e & 127, hh = e >> 7;
                uint4 v = *(const uint4*)&Sst[row*72 + c8*8];
                *(uint4*)&vt[((size_t)(b*2 + hh)*128 + d)*416 + n0] = v;
            }
        }
    }
}

// ---- fused QKV GEMM, M=64: one A-stage, 24-chunk weight stream with depth-2 register
// prefetch + LDS double-buffer (1 barrier/step), coalesced LDS-transpose epilogues ----
__global__ __launch_bounds__(256) void k_qkv(const u16* __restrict__ h,
        const u16* __restrict__ wqt, const u16* __restrict__ wkt, const u16* __restrict__ wvt,
        const float* __restrict__ bq, const float* __restrict__ bk, const float* __restrict__ bv,
        u16* __restrict__ q, u16* __restrict__ kb, u16* __restrict__ vt) {
    __shared__ __align__(16) u16 A[64*264];     // 33,792 B
    __shared__ __align__(16) u16 Wst[2][8192];  // 32,768 B
    __shared__ __align__(16) u16 Sst[4608];     //  9,216 B
    int mt = blockIdx.x, b = blockIdx.y, tid = threadIdx.x;
    const u16* srcs[3] = {wqt, wkt, wvt};
    uint4 wreg[2][4];
    auto wload = [&](int set, int i) {
        const u16* src = srcs[i >> 3] + (size_t)(i & 7)*8192;
        wreg[set][0] = *(const uint4*)&src[tid*8];
        wreg[set][1] = *(const uint4*)&src[2048 + tid*8];
        wreg[set][2] = *(const uint4*)&src[4096 + tid*8];
        wreg[set][3] = *(const uint4*)&src[6144 + tid*8];
    };
    auto wwrite = [&](int buf, int set) {
        *(uint4*)&Wst[buf][tid*8] = wreg[set][0];
        *(uint4*)&Wst[buf][2048 + tid*8] = wreg[set][1];
        *(uint4*)&Wst[buf][4096 + tid*8] = wreg[set][2];
        *(uint4*)&Wst[buf][6144 + tid*8] = wreg[set][3];
    };
    wload(0, 0);
    wload(1, 1);
    // stage A: 64 rows x 256 cols bf16 (rows >= 394 zeroed); covered by first step barrier
    #pragma unroll
    for (int it = 0; it < 8; ++it) {
        int idx = tid + it*256;
        int row = idx >> 5, seg = idx & 31;
        int n = mt*64 + row;
        uint4 val = {0,0,0,0};
        if (n < 394) val = *(const uint4*)&h[((size_t)b*394 + n)*256 + seg*8];
        *(uint4*)&A[row*264 + seg*8] = val;
    }
    int w = tid >> 6, lane = tid & 63, quad = lane >> 4, tf = lane & 15;
    f32x4 zero = {0.f,0.f,0.f,0.f};

    // ---- Q (global steps 0..7) ----
    {
        f32x4 acc[4][4];
        #pragma unroll
        for (int m = 0; m < 4; ++m)
            #pragma unroll
            for (int nf = 0; nf < 4; ++nf) acc[m][nf] = zero;
        #pragma unroll
        for (int ks = 0; ks < 8; ++ks) {
            int i = ks, buf = i & 1;
            wwrite(buf, buf);
            if (i + 2 < 24) wload(buf, i + 2);
            __syncthreads();
            short8 a0 = *(const short8*)&A[tf*264 + ks*32 + quad*8];
            short8 a1 = *(const short8*)&A[(16+tf)*264 + ks*32 + quad*8];
            short8 a2 = *(const short8*)&A[(32+tf)*264 + ks*32 + quad*8];
            short8 a3 = *(const short8*)&A[(48+tf)*264 + ks*32 + quad*8];
            #pragma unroll
            for (int nf = 0; nf < 4; ++nf) {
                short8 bb = *(const short8*)&Wst[buf][(w*64 + nf*16 + tf)*32 + quad*8];
                acc[0][nf] = MFMA(a0, bb, acc[0][nf]);
                acc[1][nf] = MFMA(a1, bb, acc[1][nf]);
                acc[2][nf] = MFMA(a2, bb, acc[2][nf]);
                acc[3][nf] = MFMA(a3, bb, acc[3][nf]);
            }
        }
        store_qk(acc, bq, q, Sst, b, mt, w, quad, tf, tid);
    }
    // ---- K (global steps 8..15) ----
    {
        f32x4 acc[4][4];
        #pragma unroll
        for (int m = 0; m < 4; ++m)
            #pragma unroll
            for (int nf = 0; nf < 4; ++nf) acc[m][nf] = zero;
        #pragma unroll
        for (int ks = 0; ks < 8; ++ks) {
            int i = 8 + ks, buf = i & 1;
            wwrite(buf, buf);
            if (i + 2 < 24) wload(buf, i + 2);
            __syncthreads();
            short8 a0 = *(const short8*)&A[tf*264 + ks*32 + quad*8];
            short8 a1 = *(const short8*)&A[(16+tf)*264 + ks*32 + quad*8];
            short8 a2 = *(const short8*)&A[(32+tf)*264 + ks*32 + quad*8];
            short8 a3 = *(const short8*)&A[(48+tf)*264 + ks*32 + quad*8];
            #pragma unroll
            for (int nf = 0; nf < 4; ++nf) {
                short8 bb = *(const short8*)&Wst[buf][(w*64 + nf*16 + tf)*32 + quad*8];
                acc[0][nf] = MFMA(a0, bb, acc[0][nf]);
                acc[1][nf] = MFMA(a1, bb, acc[1][nf]);
                acc[2][nf] = MFMA(a2, bb, acc[2][nf]);
                acc[3][nf] = MFMA(a3, bb, acc[3][nf]);
            }
        }
        store_qk(acc, bk, kb, Sst, b, mt, w, quad, tf, tid);
    }
    // ---- V (global steps 16..23; operand-swapped: acc holds transposed tile [e][n]) ----
    {
        f32x4 acc[4][4];
        #pragma unroll
        for (int m = 0; m < 4; ++m)
            #pragma unroll
            for (int nf = 0; nf < 4; ++nf) acc[m][nf] = zero;
        #pragma unroll
        for (int ks = 0; ks < 8; ++ks) {
            int i = 16 + ks, buf = i & 1;
            wwrite(buf, buf);
            if (i + 2 < 24) wload(buf, i + 2);
            __syncthreads();
            short8 a0 = *(const short8*)&A[tf*264 + ks*32 + quad*8];
            short8 a1 = *(const short8*)&A[(16+tf)*264 + ks*32 + quad*8];
            short8 a2 = *(const short8*)&A[(32+tf)*264 + ks*32 + quad*8];
            short8 a3 = *(const short8*)&A[(48+tf)*264 + ks*32 + quad*8];
            #pragma unroll
            for (int nf = 0; nf < 4; ++nf) {
                short8 bb = *(const short8*)&Wst[buf][(w*64 + nf*16 + tf)*32 + quad*8];
                acc[0][nf] = MFMA(bb, a0, acc[0][nf]);
                acc[1][nf] = MFMA(bb, a1, acc[1][nf]);
                acc[2][nf] = MFMA(bb, a2, acc[2][nf]);
                acc[3][nf] = MFMA(bb, a3, acc[3][nf]);
            }
        }
        store_v(acc, bv, vt, Sst, b, mt, w, quad, tf, tid);
    }
}

// ---- attention v6: swapped QK^T + register softmax/redistribution, K/V LDS dbuf with
// depth-2 register prefetch, XCD-grouped block swizzle, coalesced o epilogue via LDS.
__global__ __launch_bounds__(256) void k_att(const u16* __restrict__ q,
        const u16* __restrict__ kbuf, const u16* __restrict__ vt, u16* __restrict__ o) {
    __shared__ __align__(16) u16 pool[18944];   // K dbuf 2x(32x136) | V dbuf 2x(128x40); Ost reuses [0..8704)
    int nwg = gridDim.x * gridDim.y;
    int orig = blockIdx.y * gridDim.x + blockIdx.x;
    int q8 = nwg >> 3, r8 = nwg & 7;
    int xcd = orig & 7, idx = orig >> 3;
    int nid = (xcd < r8 ? xcd*(q8+1) : r8*(q8+1) + (xcd-r8)*q8) + idx;   // bijective (m204)
    int bx = nid % 7, bh = nid / 7;
    int tid = threadIdx.x;
    int w = tid >> 6, lane = tid & 63, quad = lane >> 4, tf = lane & 15;
    int mt_raw = bx*4 + w;
    int mt = mt_raw < 26 ? mt_raw : 25;
    const u16* qp = q    + (size_t)bh*53248;
    const u16* kp = kbuf + (size_t)bh*53248;
    const u16* vp = vt   + (size_t)bh*53248;
    short8 afr[4];
    #pragma unroll
    for (int ks = 0; ks < 4; ++ks)
        afr[ks] = *(const short8*)&qp[(size_t)(mt*16 + tf)*128 + ks*32 + quad*8];
    f32x4 zero = {0.f,0.f,0.f,0.f};
    f32x4 acc[25];
    #pragma unroll
    for (int nt = 0; nt < 25; ++nt) acc[nt] = zero;
    // K stage pattern: thread covers rows sr0, sr0+16 of the 32-row chunk, 16B at seg
    int sr0 = tid >> 4, sseg = tid & 15;
    uint4 kreg[2][2];
    auto kload = [&](int set, int kc) {
        kreg[set][0] = *(const uint4*)&kp[(size_t)(kc*32 + sr0)*128 + sseg*8];
        kreg[set][1] = *(const uint4*)&kp[(size_t)(kc*32 + sr0 + 16)*128 + sseg*8];
    };
    kload(0, 0);
    kload(1, 1);
    // phase 1: S^T = MFMA(K, Q): acc[nt][i] = S[n = nt*16+quad*4+i][q = mt*16+tf]
    #pragma unroll
    for (int kc = 0; kc < 13; ++kc) {
        int buf = kc & 1;
        u16* K = pool + buf*4352;
        *(uint4*)&K[sr0*136 + sseg*8] = kreg[buf][0];
        *(uint4*)&K[(sr0+16)*136 + sseg*8] = kreg[buf][1];
        if (kc + 2 < 13) kload(buf, kc + 2);
        __syncthreads();
        #pragma unroll
        for (int ncl = 0; ncl < 2; ++ncl) {
            int nt = kc*2 + ncl;
            if (nt < 25) {
                #pragma unroll
                for (int ks = 0; ks < 4; ++ks) {
                    short8 kk = *(const short8*)&K[(ncl*16 + tf)*136 + ks*32 + quad*8];
                    acc[nt] = MFMA(kk, afr[ks], acc[nt]);
                }
            }
        }
    }
    // V prologue loads (chunks 0 and 1 in flight during softmax)
    int vd0 = tid >> 2, vseg = tid & 3;
    uint4 vreg[2][2];
    auto vload = [&](int set, int kc) {
        vreg[set][0] = *(const uint4*)&vp[(size_t)vd0*416 + kc*32 + vseg*8];
        vreg[set][1] = *(const uint4*)&vp[(size_t)(vd0+64)*416 + kc*32 + vseg*8];
    };
    vload(0, 0);
    vload(1, 1);
    // phase 2: softmax over n; row q = tf is lane-local up to the quad split (2 shuffles)
    float mx = -3e38f;
    #pragma unroll
    for (int nt = 0; nt < 24; ++nt)
        #pragma unroll
        for (int i = 0; i < 4; ++i) mx = fmaxf(mx, acc[nt][i]);
    #pragma unroll
    for (int i = 0; i < 4; ++i)
        if (quad*4 + i < 10) mx = fmaxf(mx, acc[24][i]);
    mx = fmaxf(mx, __shfl_xor(mx, 16));
    mx = fmaxf(mx, __shfl_xor(mx, 32));
    float s = 0.f;
    #pragma unroll
    for (int nt = 0; nt < 24; ++nt)
        #pragma unroll
        for (int i = 0; i < 4; ++i) {
            float e = __expf(acc[nt][i] - mx);
            acc[nt][i] = e; s += e;
        }
    #pragma unroll
    for (int i = 0; i < 4; ++i) {
        if (quad*4 + i < 10) { float e = __expf(acc[24][i] - mx); acc[24][i] = e; s += e; }
        else acc[24][i] = 0.f;
    }
    s += __shfl_xor(s, 16);
    s += __shfl_xor(s, 32);
    float inv = 1.f / (16.f * s);       // softmax/sqrt(EMB)
    #pragma unroll
    for (int nt = 0; nt < 25; ++nt)
        #pragma unroll
        for (int i = 0; i < 4; ++i) acc[nt][i] *= inv;
    // phase 3: PV. Lane quad holds n-group g = 2*(quad&1)+(quad>>1) after the swap;
    // V fragment read uses the same permuted n-group so A/B contraction order matches.
    f32x4 acc2[8];
    #pragma unroll
    for (int nf = 0; nf < 8; ++nf) acc2[nf] = zero;
    int qb0 = quad & 1;
    int g = (qb0 << 1) | (quad >> 1);
    #pragma unroll
    for (int kc = 0; kc < 13; ++kc) {
        int buf = kc & 1;
        u16* V = pool + 8704 + buf*5120;
        *(uint4*)&V[vd0*40 + vseg*8] = vreg[buf][0];
        *(uint4*)&V[(vd0+64)*40 + vseg*8] = vreg[buf][1];
        if (kc + 2 < 13) vload(buf, kc + 2);
        __syncthreads();
        f32x4 v0 = acc[2*kc];
        f32x4 v1 = (kc < 12) ? acc[2*kc + 1] : zero;
        unsigned int r0 = pk2(v0[0], v0[1]);
        unsigned int r1 = pk2(v0[2], v0[3]);
        unsigned int r2 = pk2(v1[0], v1[1]);
        unsigned int r3 = pk2(v1[2], v1[3]);
        unsigned int sa = qb0 ? r0 : r2, sb = qb0 ? r1 : r3;
        unsigned int ra = (unsigned int)__shfl_xor((int)sa, 16);
        unsigned int rb = (unsigned int)__shfl_xor((int)sb, 16);
        unsigned int ka = qb0 ? r2 : r0, kb2 = qb0 ? r3 : r1;
        union { unsigned int u[4]; short8 s8; } au;
        au.u[0] = qb0 ? ra : ka;
        au.u[1] = qb0 ? rb : kb2;
        au.u[2] = qb0 ? ka : ra;
        au.u[3] = qb0 ? kb2 : rb;
        short8 a = au.s8;
        #pragma unroll
        for (int nf = 0; nf < 8; ++nf) {
            short8 bb = *(const short8*)&V[(nf*16 + tf)*40 + g*8];
            acc2[nf] = MFMA(a, bb, acc2[nf]);
        }
    }
    // epilogue: stage per-wave [16 q][136 d] tile, write 256 B contiguous per token row
    int b = bh >> 1, hh = bh & 1;
    __syncthreads();
    #pragma unroll
    for (int nf = 0; nf < 8; ++nf)
        #pragma unroll
        for (int i = 0; i < 4; ++i)
            pool[w*2176 + (quad*4 + i)*136 + nf*16 + tf] = f2b(acc2[nf][i]);
    __syncthreads();
    if (mt_raw < 26) {
        #pragma unroll
        for (int r4 = 0; r4 < 4; ++r4) {
            int rr = r4*4 + (lane >> 4);
            int n = mt_raw*16 + rr;
            if (n < 394) {
                int c16 = lane & 15;
                uint4 v = *(const uint4*)&pool[w*2176 + rr*136 + c16*8];
                *(uint4*)&o[((size_t)b*394 + n)*256 + hh*128 + c16*8] = v;
            }
        }
    }
}

// ---- proj GEMM (M=32) + LN2 + residual into z; W chunk-staged ----
__global__ __launch_bounds__(256) void k_proj(const u16* __restrict__ o,
        const u16* __restrict__ wpt, const float* __restrict__ bp,
        const float* __restrict__ g2, const float* __restrict__ bb2,
        float* __restrict__ z) {
    __shared__ __align__(16) u16 A[32*264];
    __shared__ __align__(16) u16 Wst[8192];
    __shared__ __align__(16) float S[32*260];
    int mt = blockIdx.x, b = blockIdx.y, tid = threadIdx.x;
    int w = tid >> 6, lane = tid & 63, quad = lane >> 4, tf = lane & 15;
    uint4 wr0 = *(const uint4*)&wpt[tid*8];
    uint4 wr1 = *(const uint4*)&wpt[2048 + tid*8];
    uint4 wr2 = *(const uint4*)&wpt[4096 + tid*8];
    uint4 wr3 = *(const uint4*)&wpt[6144 + tid*8];
    auto stage = [&](const u16* base, int chunk) {
        __syncthreads();
        *(uint4*)&Wst[tid*8] = wr0;
        *(uint4*)&Wst[2048 + tid*8] = wr1;
        *(uint4*)&Wst[4096 + tid*8] = wr2;
        *(uint4*)&Wst[6144 + tid*8] = wr3;
        __syncthreads();
        if (base) {
            const u16* src = base + (size_t)chunk*8192;
            wr0 = *(const uint4*)&src[tid*8];
            wr1 = *(const uint4*)&src[2048 + tid*8];
            wr2 = *(const uint4*)&src[4096 + tid*8];
            wr3 = *(const uint4*)&src[6144 + tid*8];
        }
    };
    for (int idx = tid; idx < 2048; idx += 256) {
        int row = idx >> 6, col4 = (idx & 63) * 4;
        int n = mt*32 + row;
        us4 val = {0,0,0,0};
        if (n < 394) val = *(const us4*)&o[((size_t)b*394 + n)*256 + col4];
        *(us4*)&A[row*264 + col4] = val;
    }
    f32x4 zero = {0.f,0.f,0.f,0.f};
    f32x4 acc[2][4];
    #pragma unroll
    for (int m = 0; m < 2; ++m)
        #pragma unroll
        for (int nf = 0; nf < 4; ++nf) acc[m][nf] = zero;
    #pragma unroll
    for (int ks = 0; ks < 8; ++ks) {
        stage(ks < 7 ? wpt : nullptr, ks + 1);
        short8 a0 = *(const short8*)&A[tf*264 + ks*32 + quad*8];
        short8 a1 = *(const short8*)&A[(16+tf)*264 + ks*32 + quad*8];
        #pragma unroll
        for (int nf = 0; nf < 4; ++nf) {
            short8 bb = *(const short8*)&Wst[(w*64 + nf*16 + tf)*32 + quad*8];
            acc[0][nf] = MFMA(a0, bb, acc[0][nf]);
            acc[1][nf] = MFMA(a1, bb, acc[1][nf]);
        }
    }
    #pragma unroll
    for (int nf = 0; nf < 4; ++nf) {
        int e = w*64 + nf*16 + tf;
        float bsv = bp[e];
        #pragma unroll
        for (int m = 0; m < 2; ++m)
            #pragma unroll
            for (int i = 0; i < 4; ++i)
                S[(m*16 + quad*4 + i)*260 + e] = acc[m][nf][i] + bsv;
    }
    __syncthreads();
    #pragma unroll
    for (int rr = 0; rr < 8; ++rr) {
        int row = w*8 + rr;
        f32x4 v = *(const f32x4*)&S[row*260 + lane*4];
        float s = v[0]+v[1]+v[2]+v[3];
        float sq = v[0]*v[0]+v[1]*v[1]+v[2]*v[2]+v[3]*v[3];
        #pragma unroll
        for (int m = 1; m < 64; m <<= 1) { s += __shfl_xor(s, m); sq += __shfl_xor(sq, m); }
        float mean = s*(1.f/256.f);
        float rs = rsqrtf(sq*(1.f/256.f) - mean*mean + 1e-5f);
        int n = mt*32 + row;
        if (n < 394) {
            float* zr = z + ((size_t)b*394 + n)*256 + lane*4;
            f32x4 zv = *(f32x4*)zr;
            #pragma unroll
            for (int c = 0; c < 4; ++c) {
                int e = lane*4 + c;
                zv[c] += (v[c]-mean)*rs*g2[e] + bb2[e];
            }
            *(f32x4*)zr = zv;
        }
    }
}

// ---- mean-pool split: partial n-range sums (4 blocks/image, deterministic) ----
__global__ __launch_bounds__(256) void k_poolsum(const float* __restrict__ z,
        float* __restrict__ partial) {
    int g = blockIdx.x, b = blockIdx.y, e = threadIdx.x;
    int nb = gridDim.y;
    int n0 = g*99, n1 = 394 < n0+99 ? 394 : n0+99;
    const float* zp = z + (size_t)b*394*256 + e;
    float p0 = 0.f, p1 = 0.f, p2 = 0.f, p3 = 0.f;
    int n = n0;
    for (; n + 3 < n1; n += 4) {
        p0 += zp[(size_t)n*256];       p1 += zp[(size_t)(n+1)*256];
        p2 += zp[(size_t)(n+2)*256];   p3 += zp[(size_t)(n+3)*256];
    }
    for (; n < n1; ++n) p0 += zp[(size_t)n*256];
    partial[((size_t)g*nb + b)*256 + e] = (p0+p1)+(p2+p3);
}

// ---- LNc + classifier + log_softmax over combined partials ----
__global__ __launch_bounds__(256) void k_pool2(const float* __restrict__ partial,
        const float* __restrict__ lg, const float* __restrict__ lb,
        const float* __restrict__ wc, const float* __restrict__ bc,
        float* __restrict__ out, int nb) {
    __shared__ float red[8];
    int b = blockIdx.x, e = threadIdx.x;
    int wave = e >> 6, lane = e & 63;
    float pooled = (partial[((size_t)0*nb + b)*256 + e] + partial[((size_t)1*nb + b)*256 + e]
                  + partial[((size_t)2*nb + b)*256 + e] + partial[((size_t)3*nb + b)*256 + e])
                 * (1.f/394.f);
    float a = pooled, sq = pooled*pooled;
    #pragma unroll
    for (int m = 1; m < 64; m <<= 1) { a += __shfl_xor(a, m); sq += __shfl_xor(sq, m); }
    if (lane == 0) { red[wave] = a; red[4+wave] = sq; }
    __syncthreads();
    float tot = red[0]+red[1]+red[2]+red[3];
    float totq = red[4]+red[5]+red[6]+red[7];
    float mean = tot*(1.f/256.f);
    float rs = rsqrtf(totq*(1.f/256.f) - mean*mean + 1e-5f);
    float ln = (pooled-mean)*rs*lg[e] + lb[e];
    float t0 = ln * wc[e*2], t1 = ln * wc[e*2+1];
    #pragma unroll
    for (int m = 1; m < 64; m <<= 1) { t0 += __shfl_xor(t0, m); t1 += __shfl_xor(t1, m); }
    __syncthreads();
    if (lane == 0) { red[wave] = t0; red[4+wave] = t1; }
    __syncthreads();
    if (e < 2) {
        float l0 = red[0]+red[1]+red[2]+red[3] + bc[0];
        float l1 = red[4]+red[5]+red[6]+red[7] + bc[1];
        float mx = fmaxf(l0, l1);
        float lse = mx + logf(__expf(l0-mx) + __expf(l1-mx));
        out[b*2 + e] = (e == 0 ? l0 : l1) - lse;
    }
}

extern "C" void kernel_launch(void* const* d_in, const int* in_sizes, int n_in,
                              void* d_out, int out_size, void* d_ws, size_t ws_size,
                              hipStream_t stream) {
    const float* x    = (const float*)d_in[0];
    const float* W1   = (const float*)d_in[1];
    const float* b1   = (const float*)d_in[2];
    const float* cls1 = (const float*)d_in[3];
    const float* W2   = (const float*)d_in[4];
    const float* b2   = (const float*)d_in[5];
    const float* cls2 = (const float*)d_in[6];
    const float* ln1g = (const float*)d_in[7];
    const float* ln1b = (const float*)d_in[8];
    const float* Wq   = (const float*)d_in[9];
    const float* bq   = (const float*)d_in[10];
    const float* Wk   = (const float*)d_in[11];
    const float* bk   = (const float*)d_in[12];
    const float* Wv   = (const float*)d_in[13];
    const float* bv   = (const float*)d_in[14];
    const float* Wp   = (const float*)d_in[15];
    const float* bp   = (const float*)d_in[16];
    const float* ln2g = (const float*)d_in[17];
    const float* ln2b = (const float*)d_in[18];
    const float* lncg = (const float*)d_in[19];
    const float* lncb = (const float*)d_in[20];
    const float* Wc   = (const float*)d_in[21];
    const float* bcp  = (const float*)d_in[22];

    int Bn = in_sizes[0] / (3*224*224);

    // ws: [weights 1,015,808 B][per-img: z 403456 | h/o 201728 | q 212992 | kb 212992 | vt 212992 | partial 4096]
    // A1 (im2col, [bc*208][768] bf16) aliases the q+kb region (written later by k_qkv).
    const size_t WBYTES = 1015808;
    const size_t PER_IMG = 403456 + 201728 + 212992*3 + 4096;   // 1,248,256 B
    size_t avail = (ws_size > WBYTES) ? ws_size - WBYTES : 0;
    int Bc = (int)(avail / PER_IMG);
    if (Bc < 1) Bc = 1;
    if (Bc > Bn) Bc = Bn;

    u16* w1t = (u16*)d_ws;            // [24][256][32] chunked
    u16* w2t = w1t + 196608;          // [6][256][32] chunked
    u16* wqt = w2t + 49152;           // [8][256][32] chunked, x4
    u16* wkt = wqt + 65536;
    u16* wvt = wkt + 65536;
    u16* wpt = wvt + 65536;
    float* z = (float*)(wpt + 65536);               // [Bc][394][256] f32
    u16* h   = (u16*)(z + (size_t)Bc*100864);       // [Bc][394][256]  (aliased as o)
    u16* o   = h;
    u16* q   = h + (size_t)Bc*100864;               // [Bc*2][416][128]
    u16* kb  = q + (size_t)Bc*106496;
    u16* vt  = kb + (size_t)Bc*106496;              // [Bc*2][128][416]
    float* partial = (float*)(vt + (size_t)Bc*106496);  // [4][Bc][256]

    k_wtrans<<<1984, 256, 0, stream>>>(W1, W2, Wq, Wk, Wv, Wp, w1t, w2t, wqt, wkt, wvt, wpt);

    for (int b0 = 0; b0 < Bn; b0 += Bc) {
        int bc = (Bn - b0 < Bc) ? (Bn - b0) : Bc;
        const float* xb = x + (size_t)b0 * 3*224*224;
        float* outb = (float*)d_out + (size_t)b0 * 2;
        int nrows = bc * 208;
        int gm = (nrows + 63) / 64;

        k_cls<<<bc, 256, 0, stream>>>(cls1, cls2, ln1g, ln1b, z, h);
        k_im2col1<<<dim3(13, bc), 256, 0, stream>>>(xb, q /* A1 alias */);
        k_embed1<<<gm, 256, 0, stream>>>(q /* A1 */, w1t, b1, ln1g, ln1b, z, h, nrows);
        k_embed2<<<dim3(13, bc), 256, 0, stream>>>(xb, w2t, b2, ln1g, ln1b, z, h);
        k_qkv<<<dim3(7, bc), 256, 0, stream>>>(h, wqt, wkt, wvt, bq, bk, bv, q, kb, vt);
        k_att<<<dim3(7, bc*2), 256, 0, stream>>>(q, kb, vt, o);
        k_proj<<<dim3(13, bc), 256, 0, stream>>>(o, wpt, bp, ln2g, ln2b, z);
        k_poolsum<<<dim3(4, bc), 256, 0, stream>>>(z, partial);
        k_pool2<<<bc, 256, 0, stream>>>(partial, lncg, lncb, Wc, bcp, outb, bc);
    }
}

// Round 9
// 376.451 us; speedup vs baseline: 1.4891x; 1.4891x over previous
//
#include <hip/hip_runtime.h>

typedef short short8 __attribute__((ext_vector_type(8)));
typedef float f32x4 __attribute__((ext_vector_type(4)));
typedef unsigned short us4 __attribute__((ext_vector_type(4)));
typedef unsigned short u16;

#define MFMA(a,b,c) __builtin_amdgcn_mfma_f32_16x16x32_bf16((a),(b),(c),0,0,0)

__device__ __forceinline__ u16 f2b(float f) {
    union { float f; unsigned int i; } v; v.f = f;
    unsigned int x = v.i;
    return (u16)((x + 0x7fffu + ((x >> 16) & 1u)) >> 16);
}

// pack two f32 -> one dword of 2 bf16 using the same RNE rounding as f2b
__device__ __forceinline__ unsigned int pk2(float lo, float hi) {
    return (unsigned int)f2b(lo) | ((unsigned int)f2b(hi) << 16);
}

// ---- all weights -> bf16, k-chunked layout [k>>5][256 n][32 k] (16 KB contiguous chunks);
// W1/W2 additionally permuted to channel-planar k' ----
__global__ __launch_bounds__(256) void k_wtrans(const float* __restrict__ W1,
        const float* __restrict__ W2, const float* __restrict__ Wq, const float* __restrict__ Wk,
        const float* __restrict__ Wv, const float* __restrict__ Wp,
        u16* __restrict__ w1t, u16* __restrict__ w2t, u16* __restrict__ wqt,
        u16* __restrict__ wkt, u16* __restrict__ wvt, u16* __restrict__ wpt) {
    int bx = blockIdx.x, n = threadIdx.x;
    if (bx < 768) {
        int k = bx, c = k % 3, t = k / 3, pj = t & 15, pi = t >> 4;
        int kp2 = c*256 + pi*16 + pj;
        w1t[(size_t)(kp2 >> 5)*8192 + n*32 + (kp2 & 31)] = f2b(W1[(size_t)k*256 + n]);
    } else if (bx < 960) {
        int k = bx - 768, c = k % 3, t = k / 3, pj = t & 7, pi = t >> 3;
        int kp2 = c*64 + pi*8 + pj;
        w2t[(size_t)(kp2 >> 5)*8192 + n*32 + (kp2 & 31)] = f2b(W2[(size_t)k*256 + n]);
    } else if (bx < 1216) { int k = bx - 960;  wqt[(size_t)(k>>5)*8192 + n*32 + (k&31)] = f2b(Wq[(size_t)k*256 + n]); }
    else if (bx < 1472)   { int k = bx - 1216; wkt[(size_t)(k>>5)*8192 + n*32 + (k&31)] = f2b(Wk[(size_t)k*256 + n]); }
    else if (bx < 1728)   { int k = bx - 1472; wvt[(size_t)(k>>5)*8192 + n*32 + (k&31)] = f2b(Wv[(size_t)k*256 + n]); }
    else                  { int k = bx - 1728; wpt[(size_t)(k>>5)*8192 + n*32 + (k&31)] = f2b(Wp[(size_t)k*256 + n]); }
}

// ---- cls tokens (0 = cls2, 197 = cls1) into z, fused LN1 -> h ----
__global__ __launch_bounds__(256) void k_cls(const float* __restrict__ cls1,
        const float* __restrict__ cls2, const float* __restrict__ g1, const float* __restrict__ be1,
        float* __restrict__ z, u16* __restrict__ h) {
    __shared__ float red[16];
    int b = blockIdx.x, e = threadIdx.x, lane = e & 63, w = e >> 6;
    float v0 = cls2[e], v1 = cls1[e];
    z[((size_t)b*394 + 0)*256 + e]   = v0;
    z[((size_t)b*394 + 197)*256 + e] = v1;
    float s0 = v0, q0 = v0*v0, s1 = v1, q1 = v1*v1;
    #pragma unroll
    for (int m = 1; m < 64; m <<= 1) {
        s0 += __shfl_xor(s0, m); q0 += __shfl_xor(q0, m);
        s1 += __shfl_xor(s1, m); q1 += __shfl_xor(q1, m);
    }
    if (lane == 0) { red[w] = s0; red[4+w] = q0; red[8+w] = s1; red[12+w] = q1; }
    __syncthreads();
    float S0 = red[0]+red[1]+red[2]+red[3],   Q0 = red[4]+red[5]+red[6]+red[7];
    float S1 = red[8]+red[9]+red[10]+red[11], Q1 = red[12]+red[13]+red[14]+red[15];
    float m0 = S0*(1.f/256.f), r0 = rsqrtf(Q0*(1.f/256.f) - m0*m0 + 1e-5f);
    float m1 = S1*(1.f/256.f), r1 = rsqrtf(Q1*(1.f/256.f) - m1*m1 + 1e-5f);
    h[((size_t)b*394 + 0)*256 + e]   = f2b((v0-m0)*r0*g1[e] + be1[e]);
    h[((size_t)b*394 + 197)*256 + e] = f2b((v1-m1)*r1*g1[e] + be1[e]);
}

// ---- im2col for P=16 patches: x -> A1 [bc*208][768] bf16 (k' = c*256+pi*16+pj),
// pad rows (j>=196) zeroed. Fully packed 16B stores. ----
__global__ __launch_bounds__(256) void k_im2col1(const float* __restrict__ x,
        u16* __restrict__ A1) {
    int b = blockIdx.y, g = blockIdx.x, tid = threadIdx.x;
    int p = tid >> 4, pi = tid & 15;
    int j = g*16 + p;
    u16* dst = A1 + ((size_t)b*208 + j)*768;
    if (j < 196) {
        int hi = j / 14, wi = j - hi*14;
        #pragma unroll
        for (int c = 0; c < 3; ++c) {
            const float* src = x + (((size_t)b*3 + c)*224 + hi*16 + pi)*224 + wi*16;
            f32x4 r0 = *(const f32x4*)(src);
            f32x4 r1 = *(const f32x4*)(src + 4);
            f32x4 r2 = *(const f32x4*)(src + 8);
            f32x4 r3 = *(const f32x4*)(src + 12);
            union { u16 u[16]; uint4 q[2]; } t;
            #pragma unroll
            for (int s = 0; s < 4; ++s) {
                t.u[s] = f2b(r0[s]); t.u[4+s] = f2b(r1[s]);
                t.u[8+s] = f2b(r2[s]); t.u[12+s] = f2b(r3[s]);
            }
            *(uint4*)&dst[c*256 + pi*16] = t.q[0];
            *(uint4*)&dst[c*256 + pi*16 + 8] = t.q[1];
        }
    } else {
        uint4 zer = {0,0,0,0};
        #pragma unroll
        for (int c = 0; c < 3; ++c) {
            *(uint4*)&dst[c*256 + pi*16] = zer;
            *(uint4*)&dst[c*256 + pi*16 + 8] = zer;
        }
    }
}

// ---- embed1 GEMM: [nrows x 768] x [768 x 256], M-tile 64, A/B LDS double-buffered
// (1 barrier/chunk), explicit single-set register prefetch, fused LN1 -> z, h ----
__global__ __launch_bounds__(256) void k_embed1(const u16* __restrict__ A1,
        const u16* __restrict__ w1t, const float* __restrict__ b1,
        const float* __restrict__ g1, const float* __restrict__ be1,
        float* __restrict__ z, u16* __restrict__ h, int nrows) {
    __shared__ __align__(16) u16 Ab[2][64*40];     // 10,240 B
    __shared__ __align__(16) u16 Bb[2][256*40];    // 40,960 B
    __shared__ float red[64][8];                   //  2,048 B
    int tid = threadIdx.x;
    int r0 = blockIdx.x * 64;
    int w = tid >> 6, lane = tid & 63, quad = lane >> 4, tf = lane & 15;
    int arow = tid >> 2, aoff = (tid & 3) * 8;
    const u16* ap = A1 + (size_t)(r0 + arow)*768 + aoff;
    uint4 ra  = *(const uint4*)(ap);
    uint4 rb0 = *(const uint4*)&w1t[tid*8];
    uint4 rb1 = *(const uint4*)&w1t[2048 + tid*8];
    uint4 rb2 = *(const uint4*)&w1t[4096 + tid*8];
    uint4 rb3 = *(const uint4*)&w1t[6144 + tid*8];
    f32x4 zero = {0.f,0.f,0.f,0.f};
    f32x4 acc[4][4];
    #pragma unroll
    for (int m = 0; m < 4; ++m)
        #pragma unroll
        for (int nf = 0; nf < 4; ++nf) acc[m][nf] = zero;
    #pragma unroll
    for (int kc = 0; kc < 24; ++kc) {
        int buf = kc & 1;
        *(uint4*)&Ab[buf][arow*40 + aoff] = ra;
        *(uint4*)&Bb[buf][(arow      )*40 + aoff] = rb0;
        *(uint4*)&Bb[buf][(arow +  64)*40 + aoff] = rb1;
        *(uint4*)&Bb[buf][(arow + 128)*40 + aoff] = rb2;
        *(uint4*)&Bb[buf][(arow + 192)*40 + aoff] = rb3;
        int nc = kc < 23 ? kc + 1 : 23;
        ra = *(const uint4*)(ap + nc*32);
        const u16* src = w1t + (size_t)nc*8192;
        rb0 = *(const uint4*)&src[tid*8];
        rb1 = *(const uint4*)&src[2048 + tid*8];
        rb2 = *(const uint4*)&src[4096 + tid*8];
        rb3 = *(const uint4*)&src[6144 + tid*8];
        __syncthreads();
        short8 a0 = *(const short8*)&Ab[buf][(     tf)*40 + quad*8];
        short8 a1 = *(const short8*)&Ab[buf][(16 + tf)*40 + quad*8];
        short8 a2 = *(const short8*)&Ab[buf][(32 + tf)*40 + quad*8];
        short8 a3 = *(const short8*)&Ab[buf][(48 + tf)*40 + quad*8];
        #pragma unroll
        for (int nf = 0; nf < 4; ++nf) {
            short8 bb = *(const short8*)&Bb[buf][(w*64 + nf*16 + tf)*40 + quad*8];
            acc[0][nf] = MFMA(a0, bb, acc[0][nf]);
            acc[1][nf] = MFMA(a1, bb, acc[1][nf]);
            acc[2][nf] = MFMA(a2, bb, acc[2][nf]);
            acc[3][nf] = MFMA(a3, bb, acc[3][nf]);
        }
    }
    // epilogue: bias, per-row LN via tf-shuffle partials + cross-wave LDS
    float bias[4], gv[4], bev[4];
    #pragma unroll
    for (int nf = 0; nf < 4; ++nf) {
        int n = w*64 + nf*16 + tf;
        bias[nf] = b1[n]; gv[nf] = g1[n]; bev[nf] = be1[n];
    }
    #pragma unroll
    for (int m = 0; m < 4; ++m)
        #pragma unroll
        for (int nf = 0; nf < 4; ++nf)
            #pragma unroll
            for (int i = 0; i < 4; ++i) acc[m][nf][i] += bias[nf];
    #pragma unroll
    for (int m = 0; m < 4; ++m)
        #pragma unroll
        for (int i = 0; i < 4; ++i) {
            float s = acc[m][0][i] + acc[m][1][i] + acc[m][2][i] + acc[m][3][i];
            float qv = acc[m][0][i]*acc[m][0][i] + acc[m][1][i]*acc[m][1][i]
                     + acc[m][2][i]*acc[m][2][i] + acc[m][3][i]*acc[m][3][i];
            #pragma unroll
            for (int d = 1; d < 16; d <<= 1) { s += __shfl_xor(s, d); qv += __shfl_xor(qv, d); }
            if (tf == 0) {
                red[m*16 + quad*4 + i][w] = s;
                red[m*16 + quad*4 + i][4 + w] = qv;
            }
        }
    __syncthreads();
    #pragma unroll
    for (int m = 0; m < 4; ++m)
        #pragma unroll
        for (int i = 0; i < 4; ++i) {
            int rl = m*16 + quad*4 + i;
            float S = red[rl][0]+red[rl][1]+red[rl][2]+red[rl][3];
            float Q = red[rl][4]+red[rl][5]+red[rl][6]+red[rl][7];
            float mean = S*(1.f/256.f);
            float rs = rsqrtf(Q*(1.f/256.f) - mean*mean + 1e-5f);
            int row = r0 + rl;
            if (row < nrows) {
                int img = row / 208;
                int j = row - img*208;
                if (j < 196) {
                    size_t base = ((size_t)img*394 + 198 + j)*256;
                    #pragma unroll
                    for (int nf = 0; nf < 4; ++nf) {
                        int n = w*64 + nf*16 + tf;
                        float v = acc[m][nf][i];
                        z[base + n] = v;
                        h[base + n] = f2b((v - mean)*rs*gv[nf] + bev[nf]);
                    }
                }
            }
        }
}

// ---- patch embed P=8 sampled (tokens 1..196, patch=4*it-1) + fused LN1 ----
__global__ __launch_bounds__(256) void k_embed2(const float* __restrict__ x,
        const u16* __restrict__ w2t, const float* __restrict__ b2,
        const float* __restrict__ g1, const float* __restrict__ be1,
        float* __restrict__ z, u16* __restrict__ h) {
    __shared__ __align__(16) u16 A[16*200];
    __shared__ __align__(16) u16 Wst[8192];
    __shared__ __align__(16) float S[16*260];
    int b = blockIdx.y, g = blockIdx.x, tid = threadIdx.x;
    int p = tid >> 4, s16 = tid & 15;
    int pi = s16 >> 1, ph = s16 & 1;
    int it = g*16 + p + 1;
    uint4 wr0 = *(const uint4*)&w2t[tid*8];
    uint4 wr1 = *(const uint4*)&w2t[2048 + tid*8];
    uint4 wr2 = *(const uint4*)&w2t[4096 + tid*8];
    uint4 wr3 = *(const uint4*)&w2t[6144 + tid*8];
    auto stage = [&](const u16* base, int chunk) {
        __syncthreads();
        *(uint4*)&Wst[tid*8] = wr0;
        *(uint4*)&Wst[2048 + tid*8] = wr1;
        *(uint4*)&Wst[4096 + tid*8] = wr2;
        *(uint4*)&Wst[6144 + tid*8] = wr3;
        __syncthreads();
        if (base) {
            const u16* src = base + (size_t)chunk*8192;
            wr0 = *(const uint4*)&src[tid*8];
            wr1 = *(const uint4*)&src[2048 + tid*8];
            wr2 = *(const uint4*)&src[4096 + tid*8];
            wr3 = *(const uint4*)&src[6144 + tid*8];
        }
    };
    if (it <= 196) {
        int patch = 4*it - 1;
        int hi = patch / 28, wi = patch - hi*28;
        #pragma unroll
        for (int c = 0; c < 3; ++c) {
            const float* src = x + (((size_t)b*3 + c)*224 + hi*8 + pi)*224 + wi*8 + ph*4;
            f32x4 r = *(const f32x4*)src;
            us4 o; o[0] = f2b(r[0]); o[1] = f2b(r[1]); o[2] = f2b(r[2]); o[3] = f2b(r[3]);
            *(us4*)&A[p*200 + c*64 + pi*8 + ph*4] = o;
        }
    } else {
        us4 zer = {0,0,0,0};
        #pragma unroll
        for (int c = 0; c < 3; ++c)
            *(us4*)&A[p*200 + c*64 + pi*8 + ph*4] = zer;
    }
    int w = tid >> 6, lane = tid & 63, quad = lane >> 4, tf = lane & 15;
    f32x4 zero = {0.f,0.f,0.f,0.f};
    f32x4 acc[4] = {zero,zero,zero,zero};
    #pragma unroll
    for (int ks = 0; ks < 6; ++ks) {
        stage(ks < 5 ? w2t : nullptr, ks + 1);
        short8 a = *(const short8*)&A[tf*200 + ks*32 + quad*8];
        #pragma unroll
        for (int nf = 0; nf < 4; ++nf) {
            short8 bb = *(const short8*)&Wst[(w*64 + nf*16 + tf)*32 + quad*8];
            acc[nf] = MFMA(a, bb, acc[nf]);
        }
    }
    #pragma unroll
    for (int nf = 0; nf < 4; ++nf) {
        int n = w*64 + nf*16 + tf;
        float bias = b2[n];
        #pragma unroll
        for (int i = 0; i < 4; ++i)
            S[(quad*4 + i)*260 + n] = acc[nf][i] + bias;
    }
    __syncthreads();
    #pragma unroll
    for (int rr = 0; rr < 4; ++rr) {
        int row = w*4 + rr;
        int it2 = g*16 + row + 1;
        f32x4 v = *(const f32x4*)&S[row*260 + lane*4];
        float s = v[0]+v[1]+v[2]+v[3];
        float sq = v[0]*v[0]+v[1]*v[1]+v[2]*v[2]+v[3]*v[3];
        #pragma unroll
        for (int m = 1; m < 64; m <<= 1) { s += __shfl_xor(s, m); sq += __shfl_xor(sq, m); }
        float mean = s*(1.f/256.f);
        float rs = rsqrtf(sq*(1.f/256.f) - mean*mean + 1e-5f);
        if (it2 <= 196) {
            size_t base = ((size_t)b*394 + it2)*256 + lane*4;
            *(f32x4*)&z[base] = v;
            us4 ho;
            #pragma unroll
            for (int c = 0; c < 4; ++c) {
                int e = lane*4 + c;
                ho[c] = f2b((v[c]-mean)*rs*g1[e] + be1[e]);
            }
            *(us4*)&h[base] = ho;
        }
    }
}

// ---- coalesced epilogues: stage MFMA fragments through LDS, write full lines ----
__device__ __forceinline__ void store_qk(f32x4 acc[4][4], const float* __restrict__ bs,
        u16* __restrict__ dst, u16* Sst, int b, int mt, int w, int quad, int tf, int tid) {
    #pragma unroll
    for (int m = 0; m < 4; ++m) {
        __syncthreads();
        #pragma unroll
        for (int nf = 0; nf < 4; ++nf) {
            int e = w*64 + nf*16 + tf;
            float bias = bs[e];
            #pragma unroll
            for (int i = 0; i < 4; ++i) {
                int n = mt*64 + m*16 + quad*4 + i;
                Sst[(quad*4 + i)*264 + e] = (n < 394) ? f2b(acc[m][nf][i] + bias) : (u16)0;
            }
        }
        __syncthreads();
        int row = tid >> 4, c16 = tid & 15;
        int n = mt*64 + m*16 + row;
        if (n < 416) {
            int e0 = c16*16, hh = e0 >> 7, d0 = e0 & 127;
            uint4 v0 = *(const uint4*)&Sst[row*264 + e0];
            uint4 v1 = *(const uint4*)&Sst[row*264 + e0 + 8];
            u16* p = dst + ((size_t)(b*2 + hh)*416 + n)*128 + d0;
            *(uint4*)p = v0;
            *(uint4*)(p + 8) = v1;
        }
    }
}

__device__ __forceinline__ void store_v(f32x4 acc[4][4], const float* __restrict__ bs,
        u16* __restrict__ vt, u16* Sst, int b, int mt, int w, int quad, int tf, int tid) {
    #pragma unroll
    for (int nf = 0; nf < 4; ++nf) {
        __syncthreads();
        #pragma unroll
        for (int i = 0; i < 4; ++i) {
            int e = w*64 + nf*16 + quad*4 + i;
            float bias = bs[e];
            #pragma unroll
            for (int m = 0; m < 4; ++m) {
                int n = mt*64 + m*16 + tf;
                Sst[(w*16 + quad*4 + i)*72 + m*16 + tf] = (n < 394) ? f2b(acc[m][nf][i] + bias) : (u16)0;
            }
        }
        __syncthreads();
        #pragma unroll
        for (int k = 0; k < 2; ++k) {
            int ch = tid + k*256;
            int row = ch >> 3, c8 = ch & 7;
            int n0 = mt*64 + c8*8;
            if (n0 < 416) {
                int e = (row >> 4)*64 + nf*16 + (row & 15);
                int d = e & 127, hh = e >> 7;
                uint4 v = *(const uint4*)&Sst[row*72 + c8*8];
                *(uint4*)&vt[((size_t)(b*2 + hh)*128 + d)*416 + n0] = v;
            }
        }
    }
}

// ---- fused QKV GEMM, M=64: 24-chunk weight stream, depth-2 register prefetch with
// EXPLICIT named register sets (rule #20: no runtime-indexed reg arrays), LDS dbuf,
// 1 barrier/step, coalesced LDS-transpose epilogues ----
__global__ __launch_bounds__(256) void k_qkv(const u16* __restrict__ h,
        const u16* __restrict__ wqt, const u16* __restrict__ wkt, const u16* __restrict__ wvt,
        const float* __restrict__ bq, const float* __restrict__ bk, const float* __restrict__ bv,
        u16* __restrict__ q, u16* __restrict__ kb, u16* __restrict__ vt) {
    __shared__ __align__(16) u16 A[64*264];     // 33,792 B
    __shared__ __align__(16) u16 Wst[2][8192];  // 32,768 B
    __shared__ __align__(16) u16 Sst[4608];     //  9,216 B
    int mt = blockIdx.x, b = blockIdx.y, tid = threadIdx.x;
    // chunk i (0..23) -> source pointer; i is always compile-time below
    auto cptr = [&](int i) -> const u16* {
        return i < 8 ? wqt + (size_t)i*8192
             : i < 16 ? wkt + (size_t)(i-8)*8192
                      : wvt + (size_t)(i-16)*8192;
    };
    uint4 wa0, wa1, wa2, wa3;   // even-step chunk (-> Wst[0])
    uint4 wb0, wb1, wb2, wb3;   // odd-step chunk  (-> Wst[1])
    auto loadA = [&](const u16* src) {
        wa0 = *(const uint4*)&src[tid*8];
        wa1 = *(const uint4*)&src[2048 + tid*8];
        wa2 = *(const uint4*)&src[4096 + tid*8];
        wa3 = *(const uint4*)&src[6144 + tid*8];
    };
    auto loadB = [&](const u16* src) {
        wb0 = *(const uint4*)&src[tid*8];
        wb1 = *(const uint4*)&src[2048 + tid*8];
        wb2 = *(const uint4*)&src[4096 + tid*8];
        wb3 = *(const uint4*)&src[6144 + tid*8];
    };
    auto writeA = [&]() {
        *(uint4*)&Wst[0][tid*8] = wa0;
        *(uint4*)&Wst[0][2048 + tid*8] = wa1;
        *(uint4*)&Wst[0][4096 + tid*8] = wa2;
        *(uint4*)&Wst[0][6144 + tid*8] = wa3;
    };
    auto writeB = [&]() {
        *(uint4*)&Wst[1][tid*8] = wb0;
        *(uint4*)&Wst[1][2048 + tid*8] = wb1;
        *(uint4*)&Wst[1][4096 + tid*8] = wb2;
        *(uint4*)&Wst[1][6144 + tid*8] = wb3;
    };
    loadA(cptr(0));
    loadB(cptr(1));
    // stage A: 64 rows x 256 cols bf16 (rows >= 394 zeroed); covered by first step barrier
    #pragma unroll
    for (int it = 0; it < 8; ++it) {
        int idx = tid + it*256;
        int row = idx >> 5, seg = idx & 31;
        int n = mt*64 + row;
        uint4 val = {0,0,0,0};
        if (n < 394) val = *(const uint4*)&h[((size_t)b*394 + n)*256 + seg*8];
        *(uint4*)&A[row*264 + seg*8] = val;
    }
    int w = tid >> 6, lane = tid & 63, quad = lane >> 4, tf = lane & 15;
    f32x4 zero = {0.f,0.f,0.f,0.f};

    // ---- Q (global steps 0..7) ----
    {
        f32x4 acc[4][4];
        #pragma unroll
        for (int m = 0; m < 4; ++m)
            #pragma unroll
            for (int nf = 0; nf < 4; ++nf) acc[m][nf] = zero;
        #pragma unroll
        for (int ks = 0; ks < 8; ++ks) {
            int i = ks, buf = ks & 1;
            if (buf == 0) writeA(); else writeB();
            if (i + 2 < 24) { if (buf == 0) loadA(cptr(i + 2)); else loadB(cptr(i + 2)); }
            __syncthreads();
            short8 a0 = *(const short8*)&A[tf*264 + ks*32 + quad*8];
            short8 a1 = *(const short8*)&A[(16+tf)*264 + ks*32 + quad*8];
            short8 a2 = *(const short8*)&A[(32+tf)*264 + ks*32 + quad*8];
            short8 a3 = *(const short8*)&A[(48+tf)*264 + ks*32 + quad*8];
            #pragma unroll
            for (int nf = 0; nf < 4; ++nf) {
                short8 bb = *(const short8*)&Wst[buf][(w*64 + nf*16 + tf)*32 + quad*8];
                acc[0][nf] = MFMA(a0, bb, acc[0][nf]);
                acc[1][nf] = MFMA(a1, bb, acc[1][nf]);
                acc[2][nf] = MFMA(a2, bb, acc[2][nf]);
                acc[3][nf] = MFMA(a3, bb, acc[3][nf]);
            }
        }
        store_qk(acc, bq, q, Sst, b, mt, w, quad, tf, tid);
    }
    // ---- K (global steps 8..15) ----
    {
        f32x4 acc[4][4];
        #pragma unroll
        for (int m = 0; m < 4; ++m)
            #pragma unroll
            for (int nf = 0; nf < 4; ++nf) acc[m][nf] = zero;
        #pragma unroll
        for (int ks = 0; ks < 8; ++ks) {
            int i = 8 + ks, buf = ks & 1;
            if (buf == 0) writeA(); else writeB();
            if (i + 2 < 24) { if (buf == 0) loadA(cptr(i + 2)); else loadB(cptr(i + 2)); }
            __syncthreads();
            short8 a0 = *(const short8*)&A[tf*264 + ks*32 + quad*8];
            short8 a1 = *(const short8*)&A[(16+tf)*264 + ks*32 + quad*8];
            short8 a2 = *(const short8*)&A[(32+tf)*264 + ks*32 + quad*8];
            short8 a3 = *(const short8*)&A[(48+tf)*264 + ks*32 + quad*8];
            #pragma unroll
            for (int nf = 0; nf < 4; ++nf) {
                short8 bb = *(const short8*)&Wst[buf][(w*64 + nf*16 + tf)*32 + quad*8];
                acc[0][nf] = MFMA(a0, bb, acc[0][nf]);
                acc[1][nf] = MFMA(a1, bb, acc[1][nf]);
                acc[2][nf] = MFMA(a2, bb, acc[2][nf]);
                acc[3][nf] = MFMA(a3, bb, acc[3][nf]);
            }
        }
        store_qk(acc, bk, kb, Sst, b, mt, w, quad, tf, tid);
    }
    // ---- V (global steps 16..23; operand-swapped: acc holds transposed tile [e][n]) ----
    {
        f32x4 acc[4][4];
        #pragma unroll
        for (int m = 0; m < 4; ++m)
            #pragma unroll
            for (int nf = 0; nf < 4; ++nf) acc[m][nf] = zero;
        #pragma unroll
        for (int ks = 0; ks < 8; ++ks) {
            int i = 16 + ks, buf = ks & 1;
            if (buf == 0) writeA(); else writeB();
            if (i + 2 < 24) { if (buf == 0) loadA(cptr(i + 2)); else loadB(cptr(i + 2)); }
            __syncthreads();
            short8 a0 = *(const short8*)&A[tf*264 + ks*32 + quad*8];
            short8 a1 = *(const short8*)&A[(16+tf)*264 + ks*32 + quad*8];
            short8 a2 = *(const short8*)&A[(32+tf)*264 + ks*32 + quad*8];
            short8 a3 = *(const short8*)&A[(48+tf)*264 + ks*32 + quad*8];
            #pragma unroll
            for (int nf = 0; nf < 4; ++nf) {
                short8 bb = *(const short8*)&Wst[buf][(w*64 + nf*16 + tf)*32 + quad*8];
                acc[0][nf] = MFMA(bb, a0, acc[0][nf]);
                acc[1][nf] = MFMA(bb, a1, acc[1][nf]);
                acc[2][nf] = MFMA(bb, a2, acc[2][nf]);
                acc[3][nf] = MFMA(bb, a3, acc[3][nf]);
            }
        }
        store_v(acc, bv, vt, Sst, b, mt, w, quad, tf, tid);
    }
}

// ---- attention v5 (round-6 form): swapped QK^T + register softmax/redistribution,
// K/V double-buffered in LDS (1 barrier per chunk), explicit single-set prefetch regs,
// XCD-grouped block swizzle, coalesced o epilogue via LDS.
__global__ __launch_bounds__(256) void k_att(const u16* __restrict__ q,
        const u16* __restrict__ kbuf, const u16* __restrict__ vt, u16* __restrict__ o) {
    __shared__ __align__(16) u16 pool[18944];   // K dbuf 2x(32x136) | V dbuf 2x(128x40); Ost reuses [0..8704)
    int nwg = gridDim.x * gridDim.y;
    int orig = blockIdx.y * gridDim.x + blockIdx.x;
    int q8 = nwg >> 3, r8 = nwg & 7;
    int xcd = orig & 7, idx = orig >> 3;
    int nid = (xcd < r8 ? xcd*(q8+1) : r8*(q8+1) + (xcd-r8)*q8) + idx;   // bijective (m204)
    int bx = nid % 7, bh = nid / 7;
    int tid = threadIdx.x;
    int w = tid >> 6, lane = tid & 63, quad = lane >> 4, tf = lane & 15;
    int mt_raw = bx*4 + w;
    int mt = mt_raw < 26 ? mt_raw : 25;
    const u16* qp = q    + (size_t)bh*53248;
    const u16* kp = kbuf + (size_t)bh*53248;
    const u16* vp = vt   + (size_t)bh*53248;
    short8 afr[4];
    #pragma unroll
    for (int ks = 0; ks < 4; ++ks)
        afr[ks] = *(const short8*)&qp[(size_t)(mt*16 + tf)*128 + ks*32 + quad*8];
    f32x4 zero = {0.f,0.f,0.f,0.f};
    f32x4 acc[25];
    #pragma unroll
    for (int nt = 0; nt < 25; ++nt) acc[nt] = zero;
    // K stage pattern: thread covers rows sr0, sr0+16 of the 32-row chunk, 16B at seg
    int sr0 = tid >> 4, sseg = tid & 15;
    uint4 kreg0 = *(const uint4*)&kp[(size_t)sr0*128 + sseg*8];
    uint4 kreg1 = *(const uint4*)&kp[(size_t)(sr0+16)*128 + sseg*8];
    // phase 1: S^T = MFMA(K, Q): acc[nt][i] = S[n = nt*16+quad*4+i][q = mt*16+tf]
    for (int kc = 0; kc < 13; ++kc) {
        u16* K = pool + (kc & 1)*4352;
        *(uint4*)&K[sr0*136 + sseg*8] = kreg0;
        *(uint4*)&K[(sr0+16)*136 + sseg*8] = kreg1;
        if (kc < 12) {
            kreg0 = *(const uint4*)&kp[(size_t)((kc+1)*32 + sr0)*128 + sseg*8];
            kreg1 = *(const uint4*)&kp[(size_t)((kc+1)*32 + sr0 + 16)*128 + sseg*8];
        }
        __syncthreads();
        #pragma unroll
        for (int ncl = 0; ncl < 2; ++ncl) {
            int nt = kc*2 + ncl;
            if (nt < 25) {
                #pragma unroll
                for (int ks = 0; ks < 4; ++ks) {
                    short8 kk = *(const short8*)&K[(ncl*16 + tf)*136 + ks*32 + quad*8];
                    acc[nt] = MFMA(kk, afr[ks], acc[nt]);
                }
            }
        }
    }
    // V prologue loads (in flight during softmax): thread covers d-rows vd0, vd0+64
    int vd0 = tid >> 2, vseg = tid & 3;
    uint4 vreg0 = *(const uint4*)&vp[(size_t)vd0*416 + vseg*8];
    uint4 vreg1 = *(const uint4*)&vp[(size_t)(vd0+64)*416 + vseg*8];
    // phase 2: softmax over n; row q = tf is lane-local up to the quad split (2 shuffles)
    float mx = -3e38f;
    #pragma unroll
    for (int nt = 0; nt < 24; ++nt)
        #pragma unroll
        for (int i = 0; i < 4; ++i) mx = fmaxf(mx, acc[nt][i]);
    #pragma unroll
    for (int i = 0; i < 4; ++i)
        if (quad*4 + i < 10) mx = fmaxf(mx, acc[24][i]);
    mx = fmaxf(mx, __shfl_xor(mx, 16));
    mx = fmaxf(mx, __shfl_xor(mx, 32));
    float s = 0.f;
    #pragma unroll
    for (int nt = 0; nt < 24; ++nt)
        #pragma unroll
        for (int i = 0; i < 4; ++i) {
            float e = __expf(acc[nt][i] - mx);
            acc[nt][i] = e; s += e;
        }
    #pragma unroll
    for (int i = 0; i < 4; ++i) {
        if (quad*4 + i < 10) { float e = __expf(acc[24][i] - mx); acc[24][i] = e; s += e; }
        else acc[24][i] = 0.f;
    }
    s += __shfl_xor(s, 16);
    s += __shfl_xor(s, 32);
    float inv = 1.f / (16.f * s);       // softmax/sqrt(EMB)
    #pragma unroll
    for (int nt = 0; nt < 25; ++nt)
        #pragma unroll
        for (int i = 0; i < 4; ++i) acc[nt][i] *= inv;
    // phase 3: PV. Lane quad holds n-group g = 2*(quad&1)+(quad>>1) after the swap;
    // V fragment read uses the same permuted n-group so A/B contraction order matches.
    f32x4 acc2[8];
    #pragma unroll
    for (int nf = 0; nf < 8; ++nf) acc2[nf] = zero;
    int qb0 = quad & 1;
    int g = (qb0 << 1) | (quad >> 1);
    for (int kc = 0; kc < 13; ++kc) {
        u16* V = pool + 8704 + (kc & 1)*5120;
        *(uint4*)&V[vd0*40 + vseg*8] = vreg0;
        *(uint4*)&V[(vd0+64)*40 + vseg*8] = vreg1;
        if (kc < 12) {
            vreg0 = *(const uint4*)&vp[(size_t)vd0*416 + (kc+1)*32 + vseg*8];
            vreg1 = *(const uint4*)&vp[(size_t)(vd0+64)*416 + (kc+1)*32 + vseg*8];
        }
        __syncthreads();
        f32x4 v0 = acc[2*kc];
        f32x4 v1 = (kc < 12) ? acc[2*kc + 1] : zero;
        unsigned int r0 = pk2(v0[0], v0[1]);
        unsigned int r1 = pk2(v0[2], v0[3]);
        unsigned int r2 = pk2(v1[0], v1[1]);
        unsigned int r3 = pk2(v1[2], v1[3]);
        unsigned int sa = qb0 ? r0 : r2, sb = qb0 ? r1 : r3;
        unsigned int ra = (unsigned int)__shfl_xor((int)sa, 16);
        unsigned int rb = (unsigned int)__shfl_xor((int)sb, 16);
        unsigned int ka = qb0 ? r2 : r0, kb2 = qb0 ? r3 : r1;
        union { unsigned int u[4]; short8 s8; } au;
        au.u[0] = qb0 ? ra : ka;
        au.u[1] = qb0 ? rb : kb2;
        au.u[2] = qb0 ? ka : ra;
        au.u[3] = qb0 ? kb2 : rb;
        short8 a = au.s8;
        #pragma unroll
        for (int nf = 0; nf < 8; ++nf) {
            short8 bb = *(const short8*)&V[(nf*16 + tf)*40 + g*8];
            acc2[nf] = MFMA(a, bb, acc2[nf]);
        }
    }
    // epilogue: stage per-wave [16 q][136 d] tile, write 256 B contiguous per token row
    int b = bh >> 1, hh = bh & 1;
    __syncthreads();
    #pragma unroll
    for (int nf = 0; nf < 8; ++nf)
        #pragma unroll
        for (int i = 0; i < 4; ++i)
            pool[w*2176 + (quad*4 + i)*136 + nf*16 + tf] = f2b(acc2[nf][i]);
    __syncthreads();
    if (mt_raw < 26) {
        #pragma unroll
        for (int r4 = 0; r4 < 4; ++r4) {
            int rr = r4*4 + (lane >> 4);
            int n = mt_raw*16 + rr;
            if (n < 394) {
                int c16 = lane & 15;
                uint4 v = *(const uint4*)&pool[w*2176 + rr*136 + c16*8];
                *(uint4*)&o[((size_t)b*394 + n)*256 + hh*128 + c16*8] = v;
            }
        }
    }
}

// ---- proj GEMM (M=32) + LN2 + residual into z; W chunk-staged ----
__global__ __launch_bounds__(256) void k_proj(const u16* __restrict__ o,
        const u16* __restrict__ wpt, const float* __restrict__ bp,
        const float* __restrict__ g2, const float* __restrict__ bb2,
        float* __restrict__ z) {
    __shared__ __align__(16) u16 A[32*264];
    __shared__ __align__(16) u16 Wst[8192];
    __shared__ __align__(16) float S[32*260];
    int mt = blockIdx.x, b = blockIdx.y, tid = threadIdx.x;
    int w = tid >> 6, lane = tid & 63, quad = lane >> 4, tf = lane & 15;
    uint4 wr0 = *(const uint4*)&wpt[tid*8];
    uint4 wr1 = *(const uint4*)&wpt[2048 + tid*8];
    uint4 wr2 = *(const uint4*)&wpt[4096 + tid*8];
    uint4 wr3 = *(const uint4*)&wpt[6144 + tid*8];
    auto stage = [&](const u16* base, int chunk) {
        __syncthreads();
        *(uint4*)&Wst[tid*8] = wr0;
        *(uint4*)&Wst[2048 + tid*8] = wr1;
        *(uint4*)&Wst[4096 + tid*8] = wr2;
        *(uint4*)&Wst[6144 + tid*8] = wr3;
        __syncthreads();
        if (base) {
            const u16* src = base + (size_t)chunk*8192;
            wr0 = *(const uint4*)&src[tid*8];
            wr1 = *(const uint4*)&src[2048 + tid*8];
            wr2 = *(const uint4*)&src[4096 + tid*8];
            wr3 = *(const uint4*)&src[6144 + tid*8];
        }
    };
    for (int idx = tid; idx < 2048; idx += 256) {
        int row = idx >> 6, col4 = (idx & 63) * 4;
        int n = mt*32 + row;
        us4 val = {0,0,0,0};
        if (n < 394) val = *(const us4*)&o[((size_t)b*394 + n)*256 + col4];
        *(us4*)&A[row*264 + col4] = val;
    }
    f32x4 zero = {0.f,0.f,0.f,0.f};
    f32x4 acc[2][4];
    #pragma unroll
    for (int m = 0; m < 2; ++m)
        #pragma unroll
        for (int nf = 0; nf < 4; ++nf) acc[m][nf] = zero;
    #pragma unroll
    for (int ks = 0; ks < 8; ++ks) {
        stage(ks < 7 ? wpt : nullptr, ks + 1);
        short8 a0 = *(const short8*)&A[tf*264 + ks*32 + quad*8];
        short8 a1 = *(const short8*)&A[(16+tf)*264 + ks*32 + quad*8];
        #pragma unroll
        for (int nf = 0; nf < 4; ++nf) {
            short8 bb = *(const short8*)&Wst[(w*64 + nf*16 + tf)*32 + quad*8];
            acc[0][nf] = MFMA(a0, bb, acc[0][nf]);
            acc[1][nf] = MFMA(a1, bb, acc[1][nf]);
        }
    }
    #pragma unroll
    for (int nf = 0; nf < 4; ++nf) {
        int e = w*64 + nf*16 + tf;
        float bsv = bp[e];
        #pragma unroll
        for (int m = 0; m < 2; ++m)
            #pragma unroll
            for (int i = 0; i < 4; ++i)
                S[(m*16 + quad*4 + i)*260 + e] = acc[m][nf][i] + bsv;
    }
    __syncthreads();
    #pragma unroll
    for (int rr = 0; rr < 8; ++rr) {
        int row = w*8 + rr;
        f32x4 v = *(const f32x4*)&S[row*260 + lane*4];
        float s = v[0]+v[1]+v[2]+v[3];
        float sq = v[0]*v[0]+v[1]*v[1]+v[2]*v[2]+v[3]*v[3];
        #pragma unroll
        for (int m = 1; m < 64; m <<= 1) { s += __shfl_xor(s, m); sq += __shfl_xor(sq, m); }
        float mean = s*(1.f/256.f);
        float rs = rsqrtf(sq*(1.f/256.f) - mean*mean + 1e-5f);
        int n = mt*32 + row;
        if (n < 394) {
            float* zr = z + ((size_t)b*394 + n)*256 + lane*4;
            f32x4 zv = *(f32x4*)zr;
            #pragma unroll
            for (int c = 0; c < 4; ++c) {
                int e = lane*4 + c;
                zv[c] += (v[c]-mean)*rs*g2[e] + bb2[e];
            }
            *(f32x4*)zr = zv;
        }
    }
}

// ---- mean-pool split: partial n-range sums (4 blocks/image, deterministic) ----
__global__ __launch_bounds__(256) void k_poolsum(const float* __restrict__ z,
        float* __restrict__ partial) {
    int g = blockIdx.x, b = blockIdx.y, e = threadIdx.x;
    int nb = gridDim.y;
    int n0 = g*99, n1 = 394 < n0+99 ? 394 : n0+99;
    const float* zp = z + (size_t)b*394*256 + e;
    float p0 = 0.f, p1 = 0.f, p2 = 0.f, p3 = 0.f;
    int n = n0;
    for (; n + 3 < n1; n += 4) {
        p0 += zp[(size_t)n*256];       p1 += zp[(size_t)(n+1)*256];
        p2 += zp[(size_t)(n+2)*256];   p3 += zp[(size_t)(n+3)*256];
    }
    for (; n < n1; ++n) p0 += zp[(size_t)n*256];
    partial[((size_t)g*nb + b)*256 + e] = (p0+p1)+(p2+p3);
}

// ---- LNc + classifier + log_softmax over combined partials ----
__global__ __launch_bounds__(256) void k_pool2(const float* __restrict__ partial,
        const float* __restrict__ lg, const float* __restrict__ lb,
        const float* __restrict__ wc, const float* __restrict__ bc,
        float* __restrict__ out, int nb) {
    __shared__ float red[8];
    int b = blockIdx.x, e = threadIdx.x;
    int wave = e >> 6, lane = e & 63;
    float pooled = (partial[((size_t)0*nb + b)*256 + e] + partial[((size_t)1*nb + b)*256 + e]
                  + partial[((size_t)2*nb + b)*256 + e] + partial[((size_t)3*nb + b)*256 + e])
                 * (1.f/394.f);
    float a = pooled, sq = pooled*pooled;
    #pragma unroll
    for (int m = 1; m < 64; m <<= 1) { a += __shfl_xor(a, m); sq += __shfl_xor(sq, m); }
    if (lane == 0) { red[wave] = a; red[4+wave] = sq; }
    __syncthreads();
    float tot = red[0]+red[1]+red[2]+red[3];
    float totq = red[4]+red[5]+red[6]+red[7];
    float mean = tot*(1.f/256.f);
    float rs = rsqrtf(totq*(1.f/256.f) - mean*mean + 1e-5f);
    float ln = (pooled-mean)*rs*lg[e] + lb[e];
    float t0 = ln * wc[e*2], t1 = ln * wc[e*2+1];
    #pragma unroll
    for (int m = 1; m < 64; m <<= 1) { t0 += __shfl_xor(t0, m); t1 += __shfl_xor(t1, m); }
    __syncthreads();
    if (lane == 0) { red[wave] = t0; red[4+wave] = t1; }
    __syncthreads();
    if (e < 2) {
        float l0 = red[0]+red[1]+red[2]+red[3] + bc[0];
        float l1 = red[4]+red[5]+red[6]+red[7] + bc[1];
        float mx = fmaxf(l0, l1);
        float lse = mx + logf(__expf(l0-mx) + __expf(l1-mx));
        out[b*2 + e] = (e == 0 ? l0 : l1) - lse;
    }
}

extern "C" void kernel_launch(void* const* d_in, const int* in_sizes, int n_in,
                              void* d_out, int out_size, void* d_ws, size_t ws_size,
                              hipStream_t stream) {
    const float* x    = (const float*)d_in[0];
    const float* W1   = (const float*)d_in[1];
    const float* b1   = (const float*)d_in[2];
    const float* cls1 = (const float*)d_in[3];
    const float* W2   = (const float*)d_in[4];
    const float* b2   = (const float*)d_in[5];
    const float* cls2 = (const float*)d_in[6];
    const float* ln1g = (const float*)d_in[7];
    const float* ln1b = (const float*)d_in[8];
    const float* Wq   = (const float*)d_in[9];
    const float* bq   = (const float*)d_in[10];
    const float* Wk   = (const float*)d_in[11];
    const float* bk   = (const float*)d_in[12];
    const float* Wv   = (const float*)d_in[13];
    const float* bv   = (const float*)d_in[14];
    const float* Wp   = (const float*)d_in[15];
    const float* bp   = (const float*)d_in[16];
    const float* ln2g = (const float*)d_in[17];
    const float* ln2b = (const float*)d_in[18];
    const float* lncg = (const float*)d_in[19];
    const float* lncb = (const float*)d_in[20];
    const float* Wc   = (const float*)d_in[21];
    const float* bcp  = (const float*)d_in[22];

    int Bn = in_sizes[0] / (3*224*224);

    // ws: [weights 1,015,808 B][per-img: z 403456 | h/o 201728 | q 212992 | kb 212992 | vt 212992 | partial 4096]
    // A1 (im2col, [bc*208][768] bf16) aliases the q+kb region (written later by k_qkv).
    const size_t WBYTES = 1015808;
    const size_t PER_IMG = 403456 + 201728 + 212992*3 + 4096;   // 1,248,256 B
    size_t avail = (ws_size > WBYTES) ? ws_size - WBYTES : 0;
    int Bc = (int)(avail / PER_IMG);
    if (Bc < 1) Bc = 1;
    if (Bc > Bn) Bc = Bn;

    u16* w1t = (u16*)d_ws;            // [24][256][32] chunked
    u16* w2t = w1t + 196608;          // [6][256][32] chunked
    u16* wqt = w2t + 49152;           // [8][256][32] chunked, x4
    u16* wkt = wqt + 65536;
    u16* wvt = wkt + 65536;
    u16* wpt = wvt + 65536;
    float* z = (float*)(wpt + 65536);               // [Bc][394][256] f32
    u16* h   = (u16*)(z + (size_t)Bc*100864);       // [Bc][394][256]  (aliased as o)
    u16* o   = h;
    u16* q   = h + (size_t)Bc*100864;               // [Bc*2][416][128]
    u16* kb  = q + (size_t)Bc*106496;
    u16* vt  = kb + (size_t)Bc*106496;              // [Bc*2][128][416]
    float* partial = (float*)(vt + (size_t)Bc*106496);  // [4][Bc][256]

    k_wtrans<<<1984, 256, 0, stream>>>(W1, W2, Wq, Wk, Wv, Wp, w1t, w2t, wqt, wkt, wvt, wpt);

    for (int b0 = 0; b0 < Bn; b0 += Bc) {
        int bc = (Bn - b0 < Bc) ? (Bn - b0) : Bc;
        const float* xb = x + (size_t)b0 * 3*224*224;
        float* outb = (float*)d_out + (size_t)b0 * 2;
        int nrows = bc * 208;
        int gm = (nrows + 63) / 64;

        k_cls<<<bc, 256, 0, stream>>>(cls1, cls2, ln1g, ln1b, z, h);
        k_im2col1<<<dim3(13, bc), 256, 0, stream>>>(xb, q /* A1 alias */);
        k_embed1<<<gm, 256, 0, stream>>>(q /* A1 */, w1t, b1, ln1g, ln1b, z, h, nrows);
        k_embed2<<<dim3(13, bc), 256, 0, stream>>>(xb, w2t, b2, ln1g, ln1b, z, h);
        k_qkv<<<dim3(7, bc), 256, 0, stream>>>(h, wqt, wkt, wvt, bq, bk, bv, q, kb, vt);
        k_att<<<dim3(7, bc*2), 256, 0, stream>>>(q, kb, vt, o);
        k_proj<<<dim3(13, bc), 256, 0, stream>>>(o, wpt, bp, ln2g, ln2b, z);
        k_poolsum<<<dim3(4, bc), 256, 0, stream>>>(z, partial);
        k_pool2<<<bc, 256, 0, stream>>>(partial, lncg, lncb, Wc, bcp, outb, bc);
    }
}